// Round 1
// baseline (345.045 us; speedup 1.0000x reference)
//
#include <hip/hip_runtime.h>
#include <math.h>

#define Bg   128
#define Nn   64
#define Tt   256
#define INF  320      // Nn + Tt
#define Hd   256
#define OUTD 128
#define Ee   2016     // Nn*(Nn-1)/2
#define TOTE (Bg*Ee)  // 258048
#define SCOLS 520     // padded 514 (Pm|Qm|Pv|Qv|pw|qw)

// ---------------- edge LUT: e -> (row, col) ----------------
__global__ void k_lut(int2* __restrict__ lut) {
    int e = blockIdx.x * 256 + threadIdx.x;
    if (e >= Ee) return;
    int r = 0;
    while ((r + 1) * (127 - (r + 1)) / 2 <= e) ++r;   // S(r)=r*(127-r)/2
    int c = r + 1 + (e - r * (127 - r) / 2);
    lut[e] = make_int2(r, c);
}

// ---------------- prefix-mean aggregation ----------------
// agg[b*64+j][f] = (sum_{i<j} x[b,i,f]) / j   (0 for j==0)
__global__ void k_agg(const float* __restrict__ topo, const float* __restrict__ temp,
                      float* __restrict__ agg) {
    int b = blockIdx.x;
    int f = threadIdx.x;        // 320 threads
    float run = 0.f;
    for (int j = 0; j < Nn; ++j) {
        float v = (j == 0) ? 0.f : run / (float)j;
        agg[(size_t)(b * Nn + j) * INF + f] = v;
        float x = (f < Nn) ? topo[(size_t)(b * Nn + j) * Nn + f]
                           : temp[(size_t)(b * Nn + j) * Tt + (f - Nn)];
        run += x;
    }
}

// ---------------- tiled fp32 GEMM: C = act(A@B + bias) ----------------
// A: MxK row-major, B: KxN row-major, C: MxN row-major. K % 16 == 0.
__global__ __launch_bounds__(256) void k_gemm(const float* __restrict__ A,
                                              const float* __restrict__ Bm,
                                              const float* __restrict__ bias,
                                              float* __restrict__ C,
                                              int M, int N, int K, int relu) {
    const int tx = threadIdx.x & 15, ty = threadIdx.x >> 4;
    const int rowBase = blockIdx.y * 64, colBase = blockIdx.x * 64;
    __shared__ float As[16][64];
    __shared__ float Bs[16][64];
    float acc[4][4] = {};
    for (int k0 = 0; k0 < K; k0 += 16) {
        #pragma unroll
        for (int s = 0; s < 4; ++s) {
            int idx = threadIdx.x + 256 * s;        // 0..1023
            int kk = idx & 15, r = idx >> 4;
            int row = rowBase + r;
            As[kk][r] = (row < M) ? A[(size_t)row * K + k0 + kk] : 0.f;
        }
        #pragma unroll
        for (int s = 0; s < 4; ++s) {
            int idx = threadIdx.x + 256 * s;
            int c = idx & 63, kk = idx >> 6;
            int col = colBase + c;
            Bs[kk][c] = (col < N) ? Bm[(size_t)(k0 + kk) * N + col] : 0.f;
        }
        __syncthreads();
        #pragma unroll
        for (int kk = 0; kk < 16; ++kk) {
            float a[4], bv[4];
            #pragma unroll
            for (int i = 0; i < 4; ++i) a[i] = As[kk][ty * 4 + i];
            #pragma unroll
            for (int j = 0; j < 4; ++j) bv[j] = Bs[kk][tx * 4 + j];
            #pragma unroll
            for (int i = 0; i < 4; ++i)
                #pragma unroll
                for (int j = 0; j < 4; ++j) acc[i][j] += a[i] * bv[j];
        }
        __syncthreads();
    }
    for (int i = 0; i < 4; ++i) {
        int row = rowBase + ty * 4 + i;
        if (row >= M) continue;
        for (int j = 0; j < 4; ++j) {
            int col = colBase + tx * 4 + j;
            if (col >= N) continue;
            float v = acc[i][j] + (bias ? bias[col] : 0.f);
            if (relu) v = fmaxf(v, 0.f);
            C[(size_t)row * N + col] = v;
        }
    }
}

// ---------------- pack head weights: Wcat[K=256][SCOLS] ----------------
__global__ void k_pack(const float* __restrict__ Wm, const float* __restrict__ Wv,
                       const float* __restrict__ Ww, float* __restrict__ Wcat) {
    int idx = blockIdx.x * 256 + threadIdx.x;
    if (idx >= Hd * SCOLS) return;
    int k = idx / SCOLS, col = idx - k * SCOLS;
    float v = 0.f;
    if (col < 128)       v = Wm[k * 128 + col];
    else if (col < 256)  v = Wm[(256 + k) * 128 + (col - 128)];
    else if (col < 384)  v = Wv[k * 128 + (col - 256)];
    else if (col < 512)  v = Wv[(256 + k) * 128 + (col - 384)];
    else if (col == 512) v = Ww[k];
    else if (col == 513) v = Ww[256 + k];
    Wcat[idx] = v;
}

// ---------------- per-edge: sim + logit ----------------
__global__ __launch_bounds__(256) void k_edge(const float* __restrict__ S,
                                              const int2* __restrict__ lut,
                                              const float* __restrict__ bm,
                                              const float* __restrict__ bv,
                                              const float* __restrict__ bw,
                                              const float* __restrict__ gu,
                                              float* __restrict__ sim,
                                              float* __restrict__ logit) {
    int wid = blockIdx.x * 4 + (threadIdx.x >> 6);
    int lane = threadIdx.x & 63;
    if (wid >= TOTE) return;
    int b = wid / Ee, el = wid - b * Ee;
    int2 rc = lut[el];
    const float* pi = S + (size_t)(b * Nn + rc.x) * SCOLS;
    const float* pj = S + (size_t)(b * Nn + rc.y) * SCOLS;
    float acc = 0.f;
    #pragma unroll
    for (int t = lane; t < OUTD; t += 64) {
        float m  = pi[t] + pj[128 + t] + bm[t];
        float vr = pi[256 + t] + pj[384 + t] + bv[t];
        float sp = (vr > 20.f) ? vr : log1pf(expf(vr));
        float var = sp + 1e-6f;
        acc += m * m / (var + 1e-8f);
    }
    #pragma unroll
    for (int off = 32; off; off >>= 1) acc += __shfl_down(acc, off);
    if (lane == 0) {
        float s  = acc * (1.f / OUTD);
        float se = expf(-0.5f * s);
        float wr = pi[512] + pj[513] + bw[0];
        float w  = 1.f / (1.f + expf(-wr));
        float u  = gu[wid];
        float g  = -logf(-logf(u));
        sim[wid]   = se;
        logit[wid] = (w + g) * 2.0f;   // / TEMPERATURE(=0.5)
    }
}

// ---------------- global softmax reductions ----------------
__global__ void k_max(const float* __restrict__ logit, float* __restrict__ red) {
    __shared__ float sm[256];
    float m = -INFINITY;
    for (int i = blockIdx.x * 256 + threadIdx.x; i < TOTE; i += 256 * 256)
        m = fmaxf(m, logit[i]);
    sm[threadIdx.x] = m; __syncthreads();
    for (int s = 128; s; s >>= 1) {
        if (threadIdx.x < s) sm[threadIdx.x] = fmaxf(sm[threadIdx.x], sm[threadIdx.x + s]);
        __syncthreads();
    }
    if (!threadIdx.x) red[blockIdx.x] = sm[0];
}
__global__ void k_max2(float* __restrict__ red) {
    __shared__ float sm[256];
    sm[threadIdx.x] = red[threadIdx.x]; __syncthreads();
    for (int s = 128; s; s >>= 1) {
        if (threadIdx.x < s) sm[threadIdx.x] = fmaxf(sm[threadIdx.x], sm[threadIdx.x + s]);
        __syncthreads();
    }
    if (!threadIdx.x) red[256] = sm[0];
}
__global__ void k_sum(const float* __restrict__ logit, float* __restrict__ red) {
    __shared__ float sm[256];
    float M = red[256];
    float a = 0.f;
    for (int i = blockIdx.x * 256 + threadIdx.x; i < TOTE; i += 256 * 256)
        a += expf(logit[i] - M);
    sm[threadIdx.x] = a; __syncthreads();
    for (int s = 128; s; s >>= 1) {
        if (threadIdx.x < s) sm[threadIdx.x] += sm[threadIdx.x + s];
        __syncthreads();
    }
    if (!threadIdx.x) red[blockIdx.x] = sm[0];
}
__global__ void k_sum2(float* __restrict__ red) {
    __shared__ float sm[256];
    sm[threadIdx.x] = red[threadIdx.x]; __syncthreads();
    for (int s = 128; s; s >>= 1) {
        if (threadIdx.x < s) sm[threadIdx.x] += sm[threadIdx.x + s];
        __syncthreads();
    }
    if (!threadIdx.x) red[257] = sm[0];
}

// ---------------- final scatter (also zero-fills) ----------------
__global__ void k_out(const float* __restrict__ sim, const float* __restrict__ logit,
                      const float* __restrict__ red, float* __restrict__ out) {
    int idx = blockIdx.x * 256 + threadIdx.x;
    if (idx >= Bg * Nn * Nn) return;
    int b = idx >> 12;
    int rem = idx & 4095;
    int r = rem >> 6, c = rem & 63;
    float v = 0.f;
    if (c > r) {
        int e = b * Ee + (r * (127 - r)) / 2 + (c - r - 1);
        float M = red[256], Ssum = red[257];
        v = sim[e] * expf(logit[e] - M) / Ssum;
    }
    out[idx] = v;
}

extern "C" void kernel_launch(void* const* d_in, const int* in_sizes, int n_in,
                              void* d_out, int out_size, void* d_ws, size_t ws_size,
                              hipStream_t stream) {
    const float* topo = (const float*)d_in[0];
    const float* temp = (const float*)d_in[1];
    const float* gu   = (const float*)d_in[2];
    const float* Wg   = (const float*)d_in[3];
    const float* bg   = (const float*)d_in[4];
    const float* Wm   = (const float*)d_in[5];
    const float* bm   = (const float*)d_in[6];
    const float* Wv   = (const float*)d_in[7];
    const float* bv   = (const float*)d_in[8];
    const float* Ww   = (const float*)d_in[9];
    const float* bw   = (const float*)d_in[10];
    float* out = (float*)d_out;

    char* ws = (char*)d_ws;
    size_t off = 0;
    auto carve = [&](size_t bytes) { char* p = ws + off; off = (off + bytes + 255) & ~(size_t)255; return p; };

    // Region1: agg (8192x320) before GEMM1, reused as S (8192x520) after GEMM2.
    char*  r1   = carve((size_t)Bg * Nn * SCOLS * 4);   // 17.04 MB
    float* agg  = (float*)r1;
    float* Sbuf = (float*)r1;
    float* h    = (float*)carve((size_t)Bg * Nn * Hd * 4);   // 8.39 MB
    float* Wcat = (float*)carve((size_t)Hd * SCOLS * 4);     // 0.53 MB
    float* sim  = (float*)carve((size_t)TOTE * 4);           // 1.03 MB
    float* lgt  = (float*)carve((size_t)TOTE * 4);           // 1.03 MB
    int2*  lut  = (int2*)carve((size_t)Ee * 8);
    float* red  = (float*)carve(258 * 4);

    k_lut<<<(Ee + 255) / 256, 256, 0, stream>>>(lut);
    k_agg<<<Bg, INF, 0, stream>>>(topo, temp, agg);
    // GEMM1: h[8192,256] = relu(agg[8192,320] @ Wg[320,256] + bg)
    k_gemm<<<dim3(Hd / 64, (Bg * Nn) / 64), 256, 0, stream>>>(agg, Wg, bg, h, Bg * Nn, Hd, INF, 1);
    k_pack<<<(Hd * SCOLS + 255) / 256, 256, 0, stream>>>(Wm, Wv, Ww, Wcat);
    // GEMM2: S[8192,520] = h[8192,256] @ Wcat[256,520]
    k_gemm<<<dim3((SCOLS + 63) / 64, (Bg * Nn) / 64), 256, 0, stream>>>(h, Wcat, nullptr, Sbuf, Bg * Nn, SCOLS, Hd, 0);
    k_edge<<<TOTE / 4, 256, 0, stream>>>(Sbuf, lut, bm, bv, bw, gu, sim, lgt);
    k_max<<<256, 256, 0, stream>>>(lgt, red);
    k_max2<<<1, 256, 0, stream>>>(red);
    k_sum<<<256, 256, 0, stream>>>(lgt, red);
    k_sum2<<<1, 256, 0, stream>>>(red);
    k_out<<<(Bg * Nn * Nn + 255) / 256, 256, 0, stream>>>(sim, lgt, red, out);
}

// Round 2
// 277.689 us; speedup vs baseline: 1.2426x; 1.2426x over previous
//
#include <hip/hip_runtime.h>
#include <math.h>

#define Bg   128
#define Nn   64
#define Tt   256
#define INF  320      // Nn + Tt
#define Hd   256
#define OUTD 128
#define Ee   2016     // Nn*(Nn-1)/2
#define TOTE (Bg*Ee)  // 258048
#define SCOLS 520     // padded 514 (Pm|Qm|Pv|Qv|pw|qw)

// ---------------- edge LUT: e -> (row, col) ----------------
__global__ void k_lut(int2* __restrict__ lut) {
    int e = blockIdx.x * 256 + threadIdx.x;
    if (e >= Ee) return;
    int r = 0;
    while ((r + 1) * (127 - (r + 1)) / 2 <= e) ++r;   // S(r)=r*(127-r)/2
    int c = r + 1 + (e - r * (127 - r) / 2);
    lut[e] = make_int2(r, c);
}

// ---------------- prefix-mean aggregation ----------------
// agg[b*64+j][f] = (sum_{i<j} x[b,i,f]) / j   (0 for j==0)
__global__ void k_agg(const float* __restrict__ topo, const float* __restrict__ temp,
                      float* __restrict__ agg) {
    int b = blockIdx.x;
    int f = threadIdx.x;        // 320 threads
    float run = 0.f;
    for (int j = 0; j < Nn; ++j) {
        float v = (j == 0) ? 0.f : run / (float)j;
        agg[(size_t)(b * Nn + j) * INF + f] = v;
        float x = (f < Nn) ? topo[(size_t)(b * Nn + j) * Nn + f]
                           : temp[(size_t)(b * Nn + j) * Tt + (f - Nn)];
        run += x;
    }
}

// ---------------- tiled fp32 GEMM: C = act(A@B + bias) ----------------
// A: MxK row-major, B: KxN row-major, C: MxN row-major. K % 16 == 0.
__global__ __launch_bounds__(256) void k_gemm(const float* __restrict__ A,
                                              const float* __restrict__ Bm,
                                              const float* __restrict__ bias,
                                              float* __restrict__ C,
                                              int M, int N, int K, int relu) {
    const int tx = threadIdx.x & 15, ty = threadIdx.x >> 4;
    const int rowBase = blockIdx.y * 64, colBase = blockIdx.x * 64;
    __shared__ float As[16][64];
    __shared__ float Bs[16][64];
    float acc[4][4] = {};
    for (int k0 = 0; k0 < K; k0 += 16) {
        #pragma unroll
        for (int s = 0; s < 4; ++s) {
            int idx = threadIdx.x + 256 * s;        // 0..1023
            int kk = idx & 15, r = idx >> 4;
            int row = rowBase + r;
            As[kk][r] = (row < M) ? A[(size_t)row * K + k0 + kk] : 0.f;
        }
        #pragma unroll
        for (int s = 0; s < 4; ++s) {
            int idx = threadIdx.x + 256 * s;
            int c = idx & 63, kk = idx >> 6;
            int col = colBase + c;
            Bs[kk][c] = (col < N) ? Bm[(size_t)(k0 + kk) * N + col] : 0.f;
        }
        __syncthreads();
        #pragma unroll
        for (int kk = 0; kk < 16; ++kk) {
            float a[4], bv[4];
            #pragma unroll
            for (int i = 0; i < 4; ++i) a[i] = As[kk][ty * 4 + i];
            #pragma unroll
            for (int j = 0; j < 4; ++j) bv[j] = Bs[kk][tx * 4 + j];
            #pragma unroll
            for (int i = 0; i < 4; ++i)
                #pragma unroll
                for (int j = 0; j < 4; ++j) acc[i][j] += a[i] * bv[j];
        }
        __syncthreads();
    }
    for (int i = 0; i < 4; ++i) {
        int row = rowBase + ty * 4 + i;
        if (row >= M) continue;
        for (int j = 0; j < 4; ++j) {
            int col = colBase + tx * 4 + j;
            if (col >= N) continue;
            float v = acc[i][j] + (bias ? bias[col] : 0.f);
            if (relu) v = fmaxf(v, 0.f);
            C[(size_t)row * N + col] = v;
        }
    }
}

// ---------------- pack head weights: Wcat[K=256][SCOLS] ----------------
__global__ void k_pack(const float* __restrict__ Wm, const float* __restrict__ Wv,
                       const float* __restrict__ Ww, float* __restrict__ Wcat) {
    int idx = blockIdx.x * 256 + threadIdx.x;
    if (idx >= Hd * SCOLS) return;
    int k = idx / SCOLS, col = idx - k * SCOLS;
    float v = 0.f;
    if (col < 128)       v = Wm[k * 128 + col];
    else if (col < 256)  v = Wm[(256 + k) * 128 + (col - 128)];
    else if (col < 384)  v = Wv[k * 128 + (col - 256)];
    else if (col < 512)  v = Wv[(256 + k) * 128 + (col - 384)];
    else if (col == 512) v = Ww[k];
    else if (col == 513) v = Ww[256 + k];
    Wcat[idx] = v;
}

// ---------------- per-edge: sim + logit (fast-math VALU) ----------------
// lane handles elements t=2*lane, 2*lane+1 via float2 loads (order-free sum).
__global__ __launch_bounds__(256) void k_edge(const float* __restrict__ S,
                                              const int2* __restrict__ lut,
                                              const float* __restrict__ bm,
                                              const float* __restrict__ bv,
                                              const float* __restrict__ bw,
                                              const float* __restrict__ gu,
                                              float* __restrict__ sim,
                                              float* __restrict__ logit) {
    int wid = blockIdx.x * 4 + (threadIdx.x >> 6);
    int lane = threadIdx.x & 63;
    int b = wid / Ee, el = wid - b * Ee;
    int2 rc = lut[el];
    const float* pif = S + (size_t)(b * Nn + rc.x) * SCOLS;
    const float* pjf = S + (size_t)(b * Nn + rc.y) * SCOLS;
    const float2* pi = (const float2*)pif;
    const float2* pj = (const float2*)pjf;
    float2 Pm  = pi[lane];                        // mean src   [0..128)
    float2 Qm  = pj[64 + lane];                   // mean dst   [128..256)
    float2 Pv  = pi[128 + lane];                  // var src    [256..384)
    float2 Qv  = pj[192 + lane];                  // var dst    [384..512)
    float2 bm2 = ((const float2*)bm)[lane];
    float2 bv2 = ((const float2*)bv)[lane];

    float m0 = Pm.x + Qm.x + bm2.x;
    float m1 = Pm.y + Qm.y + bm2.y;
    float x0 = Pv.x + Qv.x + bv2.x;
    float x1 = Pv.y + Qv.y + bv2.y;
    // softplus(x) = max(x,0) + log(1+exp(-|x|)), native exp/log
    float sp0 = fmaxf(x0, 0.f) + __logf(1.f + __expf(-fabsf(x0)));
    float sp1 = fmaxf(x1, 0.f) + __logf(1.f + __expf(-fabsf(x1)));
    float acc = m0 * m0 * __builtin_amdgcn_rcpf(sp0 + 1e-6f + 1e-8f)
              + m1 * m1 * __builtin_amdgcn_rcpf(sp1 + 1e-6f + 1e-8f);

    #pragma unroll
    for (int off = 32; off; off >>= 1) acc += __shfl_down(acc, off);

    if (lane == 0) {
        float se = __expf(acc * (-0.5f / OUTD));
        float wr = pif[512] + pjf[513] + bw[0];
        float w  = __builtin_amdgcn_rcpf(1.f + __expf(-wr));     // sigmoid
        float g  = -__logf(-__logf(gu[wid]));                     // gumbel
        sim[wid]   = se;
        logit[wid] = (w + g) * 2.0f;   // / TEMPERATURE(=0.5)
    }
}

// ---------------- global softmax reductions ----------------
__global__ void k_max(const float* __restrict__ logit, float* __restrict__ red) {
    __shared__ float sm[256];
    float m = -INFINITY;
    for (int i = blockIdx.x * 256 + threadIdx.x; i < TOTE; i += 256 * 256)
        m = fmaxf(m, logit[i]);
    sm[threadIdx.x] = m; __syncthreads();
    for (int s = 128; s; s >>= 1) {
        if (threadIdx.x < s) sm[threadIdx.x] = fmaxf(sm[threadIdx.x], sm[threadIdx.x + s]);
        __syncthreads();
    }
    if (!threadIdx.x) red[blockIdx.x] = sm[0];
}
__global__ void k_max2(float* __restrict__ red) {
    __shared__ float sm[256];
    sm[threadIdx.x] = red[threadIdx.x]; __syncthreads();
    for (int s = 128; s; s >>= 1) {
        if (threadIdx.x < s) sm[threadIdx.x] = fmaxf(sm[threadIdx.x], sm[threadIdx.x + s]);
        __syncthreads();
    }
    if (!threadIdx.x) red[256] = sm[0];
}
__global__ void k_sum(const float* __restrict__ logit, float* __restrict__ red) {
    __shared__ float sm[256];
    float M = red[256];
    float a = 0.f;
    for (int i = blockIdx.x * 256 + threadIdx.x; i < TOTE; i += 256 * 256)
        a += __expf(logit[i] - M);
    sm[threadIdx.x] = a; __syncthreads();
    for (int s = 128; s; s >>= 1) {
        if (threadIdx.x < s) sm[threadIdx.x] += sm[threadIdx.x + s];
        __syncthreads();
    }
    if (!threadIdx.x) red[blockIdx.x] = sm[0];
}
__global__ void k_sum2(float* __restrict__ red) {
    __shared__ float sm[256];
    sm[threadIdx.x] = red[threadIdx.x]; __syncthreads();
    for (int s = 128; s; s >>= 1) {
        if (threadIdx.x < s) sm[threadIdx.x] += sm[threadIdx.x + s];
        __syncthreads();
    }
    if (!threadIdx.x) red[257] = sm[0];
}

// ---------------- final scatter (also zero-fills) ----------------
__global__ void k_out(const float* __restrict__ sim, const float* __restrict__ logit,
                      const float* __restrict__ red, float* __restrict__ out) {
    int idx = blockIdx.x * 256 + threadIdx.x;
    if (idx >= Bg * Nn * Nn) return;
    int b = idx >> 12;
    int rem = idx & 4095;
    int r = rem >> 6, c = rem & 63;
    float v = 0.f;
    if (c > r) {
        int e = b * Ee + (r * (127 - r)) / 2 + (c - r - 1);
        float M = red[256], Sinv = __builtin_amdgcn_rcpf(red[257]);
        v = sim[e] * __expf(logit[e] - M) * Sinv;
    }
    out[idx] = v;
}

extern "C" void kernel_launch(void* const* d_in, const int* in_sizes, int n_in,
                              void* d_out, int out_size, void* d_ws, size_t ws_size,
                              hipStream_t stream) {
    const float* topo = (const float*)d_in[0];
    const float* temp = (const float*)d_in[1];
    const float* gu   = (const float*)d_in[2];
    const float* Wg   = (const float*)d_in[3];
    const float* bg   = (const float*)d_in[4];
    const float* Wm   = (const float*)d_in[5];
    const float* bm   = (const float*)d_in[6];
    const float* Wv   = (const float*)d_in[7];
    const float* bv   = (const float*)d_in[8];
    const float* Ww   = (const float*)d_in[9];
    const float* bw   = (const float*)d_in[10];
    float* out = (float*)d_out;

    char* ws = (char*)d_ws;
    size_t off = 0;
    auto carve = [&](size_t bytes) { char* p = ws + off; off = (off + bytes + 255) & ~(size_t)255; return p; };

    // Region1: agg (8192x320) before GEMM1, reused as S (8192x520) after GEMM2.
    char*  r1   = carve((size_t)Bg * Nn * SCOLS * 4);   // 17.04 MB
    float* agg  = (float*)r1;
    float* Sbuf = (float*)r1;
    float* h    = (float*)carve((size_t)Bg * Nn * Hd * 4);   // 8.39 MB
    float* Wcat = (float*)carve((size_t)Hd * SCOLS * 4);     // 0.53 MB
    float* sim  = (float*)carve((size_t)TOTE * 4);           // 1.03 MB
    float* lgt  = (float*)carve((size_t)TOTE * 4);           // 1.03 MB
    int2*  lut  = (int2*)carve((size_t)Ee * 8);
    float* red  = (float*)carve(258 * 4);

    k_lut<<<(Ee + 255) / 256, 256, 0, stream>>>(lut);
    k_agg<<<Bg, INF, 0, stream>>>(topo, temp, agg);
    // GEMM1: h[8192,256] = relu(agg[8192,320] @ Wg[320,256] + bg)
    k_gemm<<<dim3(Hd / 64, (Bg * Nn) / 64), 256, 0, stream>>>(agg, Wg, bg, h, Bg * Nn, Hd, INF, 1);
    k_pack<<<(Hd * SCOLS + 255) / 256, 256, 0, stream>>>(Wm, Wv, Ww, Wcat);
    // GEMM2: S[8192,520] = h[8192,256] @ Wcat[256,520]
    k_gemm<<<dim3((SCOLS + 63) / 64, (Bg * Nn) / 64), 256, 0, stream>>>(h, Wcat, nullptr, Sbuf, Bg * Nn, SCOLS, Hd, 0);
    k_edge<<<TOTE / 4, 256, 0, stream>>>(Sbuf, lut, bm, bv, bw, gu, sim, lgt);
    k_max<<<256, 256, 0, stream>>>(lgt, red);
    k_max2<<<1, 256, 0, stream>>>(red);
    k_sum<<<256, 256, 0, stream>>>(lgt, red);
    k_sum2<<<1, 256, 0, stream>>>(red);
    k_out<<<(Bg * Nn * Nn + 255) / 256, 256, 0, stream>>>(sim, lgt, red, out);
}